// Round 10
// baseline (588.912 us; speedup 1.0000x reference)
//
#include <hip/hip_runtime.h>
#include <hip/hip_bf16.h>

// Attention_50946902065218: Bahdanau-style attention
// B=256, L=196, E=2048, D=1024, A=512
// v10 pipeline:
//  k_wepack: We fp32 -> bf16, [kb][n][slot^swz(n)][e] pre-swizzled (2 MB)
//  k_bias2 : bias2[b][a] = be + bd + dec@Wd (64 blocks x 4 batches)
//  k_gemm_score (v10): 128x128 tile, 4 waves 2x2, BK=32.
//     BOTH operands staged via global_load_lds direct (no staging registers):
//       A: fp32 enc, swizzle baked into per-lane GLOBAL SOURCE address
//          (LDS dest linear, slot' = slot ^ (row&7)); cvt->bf16 on frag read.
//       B: pre-swizzled bf16 WeP, linear copy.
//     Classic 2-buf drain loop (r8-proven): stage(t+1), compute(t), barrier.
//     ~110 combined regs -> 4 waves/SIMD allowed; 49 KB LDS -> 3 blocks/CU.
//     XCD-chunked swizzle (4 nt-siblings share A-panel in L2).
//  k_softmax: sum 4 partials + mask + softmax over L -> alpha
//  k_awe   : alpha-weighted enc reduction

#define B_ 256
#define L_ 196
#define E_ 2048
#define D_ 1024
#define A_ 512
#define M_TOT (B_ * L_)   // 50176 = 392 * 128

typedef __attribute__((ext_vector_type(8))) short bf16x8;
typedef __attribute__((ext_vector_type(4))) float f32x4;

static __device__ __forceinline__ unsigned short f2bf(float f) {
    union { float f; unsigned u; } u{f};
    unsigned r = u.u + 0x7fffu + ((u.u >> 16) & 1u);   // RNE
    return (unsigned short)(r >> 16);
}
static __device__ __forceinline__ unsigned int pk2(float x, float y) {
    __hip_bfloat162 h = __float22bfloat162_rn(float2{x, y});   // v_cvt_pk_bf16_f32
    return *reinterpret_cast<unsigned int*>(&h);
}
static __device__ __forceinline__ void gload_lds16(const void* g, void* l) {
    __builtin_amdgcn_global_load_lds(
        (const __attribute__((address_space(1))) unsigned int*)g,
        (__attribute__((address_space(3))) unsigned int*)l, 16, 0, 0);
}

// ---------------- k_wepack: We (E x A fp32) -> WeP bf16 ----------------------
// (k,n): kb=k>>5, slot=(k>>3)&3, e=k&7; stored slot' = slot ^ ((n>>1)&3).
// Index = kb*16384 + n*32 + slot'*8 + e.  (measured: 0 LDS conflicts, r4/r9)
__global__ __launch_bounds__(256) void k_wepack(const float* __restrict__ We,
                                                unsigned short* __restrict__ WeP) {
    int i = blockIdx.x * 256 + threadIdx.x;
    int k = i >> 9, n = i & 511;
    int kb = k >> 5, slot = (k >> 3) & 3, e = k & 7;
    int slotE = slot ^ ((n >> 1) & 3);
    WeP[(kb << 14) + (n << 5) + (slotE << 3) + e] = f2bf(We[i]);
}

// ---------------- k_bias2: bias2 = be + bd + dec @ Wd (4 batches/block) ------
__global__ __launch_bounds__(256) void k_bias2(const float* __restrict__ dec,
                                               const float* __restrict__ Wd,
                                               const float* __restrict__ be,
                                               const float* __restrict__ bd,
                                               float* __restrict__ bias2) {
    int b0 = blockIdx.x * 4, t = threadIdx.x;
    __shared__ float ds[4][D_];
    for (int i = t; i < 4 * D_; i += 256) ds[i >> 10][i & 1023] = dec[(size_t)b0 * D_ + i];
    __syncthreads();
    #pragma unroll
    for (int p = 0; p < 2; p++) {
        int a = p * 256 + t;
        float a0 = 0.f, a1 = 0.f, a2 = 0.f, a3 = 0.f;
        #pragma unroll 4
        for (int d = 0; d < D_; d++) {
            float w = Wd[d * A_ + a];
            a0 += ds[0][d] * w; a1 += ds[1][d] * w;
            a2 += ds[2][d] * w; a3 += ds[3][d] * w;
        }
        float bb = be[a] + bd[a];
        bias2[(b0 + 0) * A_ + a] = a0 + bb;
        bias2[(b0 + 1) * A_ + a] = a1 + bb;
        bias2[(b0 + 2) * A_ + a] = a2 + bb;
        bias2[(b0 + 3) * A_ + a] = a3 + bb;
    }
}

// ---------------- k_gemm_score v10 -------------------------------------------
// 1568 blocks (392 mt x 4 nt, XCD-chunked), 256 thr, 4 waves 2x2, wave 64x64.
// LDS: A fp32 [2][128 rows][8 slots x 16B] (32 KB), B bf16 [2][4096] (16 KB).
__global__ __launch_bounds__(256, 3) void k_gemm_score(
        const float* __restrict__ enc,
        const unsigned short* __restrict__ WeP,
        const float* __restrict__ bias2,
        const float* __restrict__ wf,
        float* __restrict__ scoresP) {
    __shared__ __align__(16) float aF[2][4096];             // 16 KB each
    __shared__ __align__(16) unsigned short bL[2][4096];    // 8 KB each
    __shared__ float score_lds[4][64];

    const int tid = threadIdx.x;
    const int raw = blockIdx.x;                 // 1568 = 8 * 196
    const int wg = (raw & 7) * 196 + (raw >> 3);
    const int mt = wg >> 2, nt = wg & 3;
    const int m0 = mt * 128;

    const int lane = tid & 63, wid = tid >> 6;
    const int wm = wid >> 1, wn = wid & 1;
    const int kg = lane >> 4, lr = lane & 15;

    // A staging: 4 chunks; dest 16B-slot gidx = c*256 + tid (LINEAR in lane).
    // gidx -> (row = gidx>>3, dest slot sp = lane&7). Source k-slot for that
    // dest: s = sp ^ (row&7), and (row&7) == (lane>>3) for every chunk.
    // => per-lane global src = enc[m0+row][kb*32 + s*4 ..+4)  (16B aligned)
    const int sA = (lane & 7) ^ (lane >> 3);
    const float* aSrc0 = enc + (size_t)(m0 + (tid >> 3)) * E_ + sA * 4;
    // B staging: linear copy of the block's pre-swizzled 8 KB slice
    const unsigned short* bSrc = WeP + nt * 4096 + tid * 8;

    auto stage = [&](int kb, int buf) {
        #pragma unroll
        for (int c = 0; c < 4; c++)
            gload_lds16(aSrc0 + (size_t)c * 32 * E_ + (kb << 5),
                        &aF[buf][(c * 256 + tid) * 4]);
        const unsigned short* sb = bSrc + (kb << 14);
        gload_lds16(sb,        &bL[buf][tid * 8]);
        gload_lds16(sb + 2048, &bL[buf][2048 + tid * 8]);
    };

    f32x4 acc[4][4];
    #pragma unroll
    for (int i = 0; i < 4; i++)
        #pragma unroll
        for (int j = 0; j < 4; j++) acc[i][j] = (f32x4){0.f, 0.f, 0.f, 0.f};

    auto computeTile = [&](int buf) {
        bf16x8 bfr[4];
        #pragma unroll
        for (int j = 0; j < 4; j++) {
            int n = wn * 64 + j * 16 + lr;
            bfr[j] = *reinterpret_cast<const bf16x8*>(
                &bL[buf][n * 32 + ((kg ^ ((n >> 1) & 3)) << 3)]);
        }
        #pragma unroll
        for (int i = 0; i < 4; i++) {
            int row = wm * 64 + i * 16 + lr;
            int r7 = row & 7;                   // == lr & 7
            const float* base = &aF[buf][row * 32];
            float4 f0 = *reinterpret_cast<const float4*>(
                base + ((((kg << 1) | 0) ^ r7) << 2));
            float4 f1 = *reinterpret_cast<const float4*>(
                base + ((((kg << 1) | 1) ^ r7) << 2));
            union { uint4 q; bf16x8 v; } u;
            u.q.x = pk2(f0.x, f0.y); u.q.y = pk2(f0.z, f0.w);
            u.q.z = pk2(f1.x, f1.y); u.q.w = pk2(f1.z, f1.w);
            #pragma unroll
            for (int j = 0; j < 4; j++)
                acc[i][j] = __builtin_amdgcn_mfma_f32_16x16x32_bf16(
                    u.v, bfr[j], acc[i][j], 0, 0, 0);
        }
    };

    // --- classic 2-buf drain pipeline (r8-proven fastest) ---
    stage(0, 0);
    __syncthreads();
    int buf = 0;
    for (int kb = 0; kb < 64; kb++) {
        if (kb < 63) stage(kb + 1, buf ^ 1);
        computeTile(buf);
        __syncthreads();
        buf ^= 1;
    }

    // --- epilogue: tanh + wf dot over this block's 128 cols -> partials ---
    #pragma unroll
    for (int i = 0; i < 4; i++) {
        #pragma unroll
        for (int r = 0; r < 4; r++) {
            int Rw = i * 16 + kg * 4 + r;   // C/D: col=lane&15, row=(lane>>4)*4+reg
            int gm = m0 + wm * 64 + Rw;
            int bg = gm / L_;
            float sum = 0.f;
            #pragma unroll
            for (int j = 0; j < 4; j++) {
                int C = nt * 128 + wn * 64 + j * 16 + lr;
                float x = acc[i][j][r] + bias2[bg * A_ + C];
                float ex = __expf(2.f * x);     // tanh = 1 - 2/(e^2x + 1)
                sum += wf[C] * (1.f - 2.f * __builtin_amdgcn_rcpf(ex + 1.f));
            }
            #pragma unroll
            for (int mk = 1; mk < 16; mk <<= 1) sum += __shfl_xor(sum, mk);
            if (lr == 0) score_lds[wid][Rw] = sum;
        }
    }
    __syncthreads();
    if (tid < 128) {
        int wmp = tid >> 6, rl = tid & 63;
        float s = score_lds[wmp * 2][rl] + score_lds[wmp * 2 + 1][rl];
        scoresP[nt * M_TOT + m0 + wmp * 64 + rl] = s;
    }
}

// ---------------- k_softmax: sum 4 partials + mask + softmax -----------------
__global__ __launch_bounds__(256) void k_softmax(const float* __restrict__ scoresP,
                                                 const int* __restrict__ mask,
                                                 const float* __restrict__ bfp,
                                                 float* __restrict__ alpha) {
    int b = blockIdx.x, t = threadIdx.x;
    float bfv = bfp[0];
    float v = -INFINITY;
    if (t < L_) {
        int idx = b * L_ + t;
        float sc = scoresP[idx] + scoresP[M_TOT + idx] +
                   scoresP[2 * M_TOT + idx] + scoresP[3 * M_TOT + idx];
        v = (mask[idx] == 0) ? -1e9f : (sc + bfv);
    }
    __shared__ float redm[4], reds[4];
    float m = v;
    #pragma unroll
    for (int s = 1; s < 64; s <<= 1) m = fmaxf(m, __shfl_xor(m, s));
    int w = t >> 6;
    if ((t & 63) == 0) redm[w] = m;
    __syncthreads();
    m = fmaxf(fmaxf(redm[0], redm[1]), fmaxf(redm[2], redm[3]));
    float e = (t < L_) ? expf(v - m) : 0.f;
    float s = e;
    #pragma unroll
    for (int k = 1; k < 64; k <<= 1) s += __shfl_xor(s, k);
    if ((t & 63) == 0) reds[w] = s;
    __syncthreads();
    s = reds[0] + reds[1] + reds[2] + reds[3];
    if (t < L_) alpha[b * L_ + t] = e / s;
}

// ---------------- k_awe: awe = sum_l alpha * enc ------------------------------
// grid (8 e-chunks of 256, 256 batches), 256 threads = 4 groups x 64 lanes.
__global__ __launch_bounds__(256) void k_awe(const float* __restrict__ enc,
                                             const float* __restrict__ alpha,
                                             float* __restrict__ awe) {
    int b = blockIdx.y, ec = blockIdx.x, t = threadIdx.x;
    int g = t >> 6, lt = t & 63;
    __shared__ float al[L_];
    __shared__ float4 red[256];
    if (t < L_) al[t] = alpha[b * L_ + t];
    __syncthreads();
    int e0 = (ec << 8) + (lt << 2);
    const float* base = enc + (size_t)b * L_ * E_ + e0;
    float4 acc = {0.f, 0.f, 0.f, 0.f};
    int l0 = g * 49;
    #pragma unroll 7
    for (int l = l0; l < l0 + 49; l++) {
        float4 v = *reinterpret_cast<const float4*>(base + (size_t)l * E_);
        float a = al[l];
        acc.x += a * v.x; acc.y += a * v.y; acc.z += a * v.z; acc.w += a * v.w;
    }
    red[t] = acc;
    __syncthreads();
    if (t < 64) {
        float4 r0 = red[t], r1 = red[64 + t], r2 = red[128 + t], r3 = red[192 + t];
        float4 o;
        o.x = r0.x + r1.x + r2.x + r3.x;
        o.y = r0.y + r1.y + r2.y + r3.y;
        o.z = r0.z + r1.z + r2.z + r3.z;
        o.w = r0.w + r1.w + r2.w + r3.w;
        *reinterpret_cast<float4*>(awe + b * E_ + (ec << 8) + (t << 2)) = o;
    }
}

extern "C" void kernel_launch(void* const* d_in, const int* in_sizes, int n_in,
                              void* d_out, int out_size, void* d_ws, size_t ws_size,
                              hipStream_t stream) {
    const float* enc  = (const float*)d_in[0];
    const float* dec  = (const float*)d_in[1];
    const int*   mask = (const int*)d_in[2];
    const float* We   = (const float*)d_in[3];
    const float* be   = (const float*)d_in[4];
    const float* Wd   = (const float*)d_in[5];
    const float* bd   = (const float*)d_in[6];
    const float* wf   = (const float*)d_in[7];
    const float* bf   = (const float*)d_in[8];

    float* awe   = (float*)d_out;                  // [256][2048]
    float* alpha = awe + (size_t)B_ * E_;          // [256][196]

    char* ws = (char*)d_ws;
    unsigned short* WeP = (unsigned short*)ws;                        // 2 MB
    float* bias2   = (float*)(ws + 2097152);                          // 512 KB
    float* scoresP = (float*)(ws + 2621440);                          // 803 KB

    hipLaunchKernelGGL(k_wepack, dim3((E_ * A_) / 256), dim3(256), 0, stream, We, WeP);
    hipLaunchKernelGGL(k_bias2, dim3(B_ / 4), dim3(256), 0, stream, dec, Wd, be, bd, bias2);
    hipLaunchKernelGGL(k_gemm_score, dim3(1568), dim3(256), 0, stream,
                       enc, WeP, bias2, wf, scoresP);
    hipLaunchKernelGGL(k_softmax, dim3(B_), dim3(256), 0, stream, scoresP, mask, bf, alpha);
    hipLaunchKernelGGL(k_awe, dim3(8, B_), dim3(256), 0, stream, enc, alpha, awe);
}

// Round 11
// 558.464 us; speedup vs baseline: 1.0545x; 1.0545x over previous
//
#include <hip/hip_runtime.h>
#include <hip/hip_bf16.h>

// Attention_50946902065218: Bahdanau-style attention
// B=256, L=196, E=2048, D=1024, A=512
// v11 pipeline:
//  k_wepack: We fp32 -> bf16, [kb][n][slot^swz(n)][e] pre-swizzled (2 MB)
//  k_bias2 : bias2[b][a] = be + bd + dec@Wd (64 blocks x 4 batches)
//  k_gemm_score (v11): 128x128 tile, 4 waves 2x2, BK=32, 2-buf DRAIN loop.
//     B via global_load_lds from pre-swizzled WeP (r4/r9: 0 conflicts).
//     A reg-staged fp32->bf16 (r9's verified swizzled layout), 1-step lead.
//     33 KB LDS -> 4 blocks/CU (16 waves) -- r8's measured-best residency.
//     XCD-chunked swizzle (4 nt-siblings share A-panel in L2).
//  k_softmax: sum 4 partials + mask + softmax over L -> alpha
//  k_awe   : alpha-weighted enc reduction (r5/r9's measured version)

#define B_ 256
#define L_ 196
#define E_ 2048
#define D_ 1024
#define A_ 512
#define M_TOT (B_ * L_)   // 50176 = 392 * 128

typedef __attribute__((ext_vector_type(8))) short bf16x8;
typedef __attribute__((ext_vector_type(4))) float f32x4;

static __device__ __forceinline__ unsigned short f2bf(float f) {
    union { float f; unsigned u; } u{f};
    unsigned r = u.u + 0x7fffu + ((u.u >> 16) & 1u);   // RNE
    return (unsigned short)(r >> 16);
}
static __device__ __forceinline__ unsigned int pk2(float x, float y) {
    __hip_bfloat162 h = __float22bfloat162_rn(float2{x, y});   // v_cvt_pk_bf16_f32
    return *reinterpret_cast<unsigned int*>(&h);
}
static __device__ __forceinline__ void gload_lds16(const void* g, void* l) {
    __builtin_amdgcn_global_load_lds(
        (const __attribute__((address_space(1))) unsigned int*)g,
        (__attribute__((address_space(3))) unsigned int*)l, 16, 0, 0);
}

// ---------------- k_wepack: We (E x A fp32) -> WeP bf16 ----------------------
// (k,n): kb=k>>5, slot=(k>>3)&3, e=k&7; stored slot' = slot ^ ((n>>1)&3).
// Index = kb*16384 + n*32 + slot'*8 + e.  (measured: 0 LDS conflicts, r4/r9)
__global__ __launch_bounds__(256) void k_wepack(const float* __restrict__ We,
                                                unsigned short* __restrict__ WeP) {
    int i = blockIdx.x * 256 + threadIdx.x;
    int k = i >> 9, n = i & 511;
    int kb = k >> 5, slot = (k >> 3) & 3, e = k & 7;
    int slotE = slot ^ ((n >> 1) & 3);
    WeP[(kb << 14) + (n << 5) + (slotE << 3) + e] = f2bf(We[i]);
}

// ---------------- k_bias2: bias2 = be + bd + dec @ Wd (4 batches/block) ------
__global__ __launch_bounds__(256) void k_bias2(const float* __restrict__ dec,
                                               const float* __restrict__ Wd,
                                               const float* __restrict__ be,
                                               const float* __restrict__ bd,
                                               float* __restrict__ bias2) {
    int b0 = blockIdx.x * 4, t = threadIdx.x;
    __shared__ float ds[4][D_];
    for (int i = t; i < 4 * D_; i += 256) ds[i >> 10][i & 1023] = dec[(size_t)b0 * D_ + i];
    __syncthreads();
    #pragma unroll
    for (int p = 0; p < 2; p++) {
        int a = p * 256 + t;
        float a0 = 0.f, a1 = 0.f, a2 = 0.f, a3 = 0.f;
        #pragma unroll 4
        for (int d = 0; d < D_; d++) {
            float w = Wd[d * A_ + a];
            a0 += ds[0][d] * w; a1 += ds[1][d] * w;
            a2 += ds[2][d] * w; a3 += ds[3][d] * w;
        }
        float bb = be[a] + bd[a];
        bias2[(b0 + 0) * A_ + a] = a0 + bb;
        bias2[(b0 + 1) * A_ + a] = a1 + bb;
        bias2[(b0 + 2) * A_ + a] = a2 + bb;
        bias2[(b0 + 3) * A_ + a] = a3 + bb;
    }
}

// ---------------- k_gemm_score v11 -------------------------------------------
// 1568 blocks (392 mt x 4 nt, XCD-chunked), 256 thr, 4 waves 2x2, wave 64x64.
// LDS: A bf16 [2][4096] (16 KB), B bf16 [2][4096] (16 KB), score 1 KB = 33 KB.
__global__ __launch_bounds__(256) void k_gemm_score(
        const float* __restrict__ enc,
        const unsigned short* __restrict__ WeP,
        const float* __restrict__ bias2,
        const float* __restrict__ wf,
        float* __restrict__ scoresP) {
    __shared__ __align__(16) unsigned short aL[2][4096];    // 8 KB each
    __shared__ __align__(16) unsigned short bL[2][4096];    // 8 KB each
    __shared__ float score_lds[4][64];

    const int tid = threadIdx.x;
    const int raw = blockIdx.x;                 // 1568 = 8 * 196
    const int wg = (raw & 7) * 196 + (raw >> 3);
    const int mt = wg >> 2, nt = wg & 3;
    const int m0 = mt * 128;

    const int lane = tid & 63, wid = tid >> 6;
    const int wm = wid >> 1, wn = wid & 1;
    const int kg = lane >> 4, lr = lane & 15;

    // A staging (r9-verified layout): thread -> row ar (2 thr/row), half kh.
    // LDS row = 32 shorts (64B, 4 x 16B slots); slot' = slot ^ ((ar>>1)&3).
    const int ar = tid >> 1, kh = tid & 1;
    const float* aSrc = enc + (size_t)(m0 + ar) * E_ + kh * 16;
    const int sw = (ar >> 1) & 3;
    const int aOff0 = ar * 32 + ((((kh << 1) | 0) ^ sw) << 3);
    const int aOff1 = ar * 32 + ((((kh << 1) | 1) ^ sw) << 3);

    // B staging: 2 x gload_lds16/thread, linear 8 KB nt-slice (pre-swizzled)
    const unsigned short* bSrc = WeP + nt * 4096 + tid * 8;

    auto stageB = [&](int kb, int buf) {
        const unsigned short* s = bSrc + (kb << 14);
        gload_lds16(s,        &bL[buf][tid * 8]);
        gload_lds16(s + 2048, &bL[buf][2048 + tid * 8]);
    };
    auto loadA = [&](float4 (&v)[4], int kb) {
        const float* p = aSrc + (kb << 5);
        v[0] = *reinterpret_cast<const float4*>(p);
        v[1] = *reinterpret_cast<const float4*>(p + 4);
        v[2] = *reinterpret_cast<const float4*>(p + 8);
        v[3] = *reinterpret_cast<const float4*>(p + 12);
    };
    auto writeA = [&](const float4 (&v)[4], int buf) {
        uint4 q0, q1;
        q0.x = pk2(v[0].x, v[0].y); q0.y = pk2(v[0].z, v[0].w);
        q0.z = pk2(v[1].x, v[1].y); q0.w = pk2(v[1].z, v[1].w);
        q1.x = pk2(v[2].x, v[2].y); q1.y = pk2(v[2].z, v[2].w);
        q1.z = pk2(v[3].x, v[3].y); q1.w = pk2(v[3].z, v[3].w);
        *reinterpret_cast<uint4*>(&aL[buf][aOff0]) = q0;
        *reinterpret_cast<uint4*>(&aL[buf][aOff1]) = q1;
    };

    f32x4 acc[4][4];
    #pragma unroll
    for (int i = 0; i < 4; i++)
        #pragma unroll
        for (int j = 0; j < 4; j++) acc[i][j] = (f32x4){0.f, 0.f, 0.f, 0.f};

    auto computeTile = [&](int buf) {
        bf16x8 bfr[4];
        #pragma unroll
        for (int j = 0; j < 4; j++) {
            int n = wn * 64 + j * 16 + lr;
            bfr[j] = *reinterpret_cast<const bf16x8*>(
                &bL[buf][n * 32 + ((kg ^ ((n >> 1) & 3)) << 3)]);
        }
        #pragma unroll
        for (int i = 0; i < 4; i++) {
            int row = wm * 64 + i * 16 + lr;
            bf16x8 af = *reinterpret_cast<const bf16x8*>(
                &aL[buf][row * 32 + ((kg ^ ((row >> 1) & 3)) << 3)]);
            #pragma unroll
            for (int j = 0; j < 4; j++)
                acc[i][j] = __builtin_amdgcn_mfma_f32_16x16x32_bf16(
                    af, bfr[j], acc[i][j], 0, 0, 0);
        }
    };

    // --- 2-buf drain pipeline (r8-proven residency: 4 blocks/CU) ---
    {
        float4 av0[4];
        loadA(av0, 0);
        stageB(0, 0);
        writeA(av0, 0);
        __syncthreads();
    }
    int buf = 0;
    float4 av[4];
    for (int kb = 0; kb < 64; kb++) {
        if (kb < 63) {
            loadA(av, kb + 1);          // issue A early (global, L2/HBM)
            stageB(kb + 1, buf ^ 1);    // issue B (gload_lds, L2)
        }
        computeTile(buf);
        if (kb < 63) writeA(av, buf ^ 1);   // cvt + ds_write after compute
        __syncthreads();
        buf ^= 1;
    }

    // --- epilogue: tanh + wf dot over this block's 128 cols -> partials ---
    #pragma unroll
    for (int i = 0; i < 4; i++) {
        #pragma unroll
        for (int r = 0; r < 4; r++) {
            int Rw = i * 16 + kg * 4 + r;   // C/D: col=lane&15, row=(lane>>4)*4+reg
            int gm = m0 + wm * 64 + Rw;
            int bg = gm / L_;
            float sum = 0.f;
            #pragma unroll
            for (int j = 0; j < 4; j++) {
                int C = nt * 128 + wn * 64 + j * 16 + lr;
                float x = acc[i][j][r] + bias2[bg * A_ + C];
                float ex = __expf(2.f * x);     // tanh = 1 - 2/(e^2x + 1)
                sum += wf[C] * (1.f - 2.f * __builtin_amdgcn_rcpf(ex + 1.f));
            }
            #pragma unroll
            for (int mk = 1; mk < 16; mk <<= 1) sum += __shfl_xor(sum, mk);
            if (lr == 0) score_lds[wid][Rw] = sum;
        }
    }
    __syncthreads();
    if (tid < 128) {
        int wmp = tid >> 6, rl = tid & 63;
        float s = score_lds[wmp * 2][rl] + score_lds[wmp * 2 + 1][rl];
        scoresP[nt * M_TOT + m0 + wmp * 64 + rl] = s;
    }
}

// ---------------- k_softmax: sum 4 partials + mask + softmax -----------------
__global__ __launch_bounds__(256) void k_softmax(const float* __restrict__ scoresP,
                                                 const int* __restrict__ mask,
                                                 const float* __restrict__ bfp,
                                                 float* __restrict__ alpha) {
    int b = blockIdx.x, t = threadIdx.x;
    float bfv = bfp[0];
    float v = -INFINITY;
    if (t < L_) {
        int idx = b * L_ + t;
        float sc = scoresP[idx] + scoresP[M_TOT + idx] +
                   scoresP[2 * M_TOT + idx] + scoresP[3 * M_TOT + idx];
        v = (mask[idx] == 0) ? -1e9f : (sc + bfv);
    }
    __shared__ float redm[4], reds[4];
    float m = v;
    #pragma unroll
    for (int s = 1; s < 64; s <<= 1) m = fmaxf(m, __shfl_xor(m, s));
    int w = t >> 6;
    if ((t & 63) == 0) redm[w] = m;
    __syncthreads();
    m = fmaxf(fmaxf(redm[0], redm[1]), fmaxf(redm[2], redm[3]));
    float e = (t < L_) ? expf(v - m) : 0.f;
    float s = e;
    #pragma unroll
    for (int k = 1; k < 64; k <<= 1) s += __shfl_xor(s, k);
    if ((t & 63) == 0) reds[w] = s;
    __syncthreads();
    s = reds[0] + reds[1] + reds[2] + reds[3];
    if (t < L_) alpha[b * L_ + t] = e / s;
}

// ---------------- k_awe: awe = sum_l alpha * enc ------------------------------
// grid (8 e-chunks of 256, 256 batches), 256 threads = 4 groups x 64 lanes.
__global__ __launch_bounds__(256) void k_awe(const float* __restrict__ enc,
                                             const float* __restrict__ alpha,
                                             float* __restrict__ awe) {
    int b = blockIdx.y, ec = blockIdx.x, t = threadIdx.x;
    int g = t >> 6, lt = t & 63;
    __shared__ float al[L_];
    __shared__ float4 red[256];
    if (t < L_) al[t] = alpha[b * L_ + t];
    __syncthreads();
    int e0 = (ec << 8) + (lt << 2);
    const float* base = enc + (size_t)b * L_ * E_ + e0;
    float4 acc = {0.f, 0.f, 0.f, 0.f};
    int l0 = g * 49;
    #pragma unroll 7
    for (int l = l0; l < l0 + 49; l++) {
        float4 v = *reinterpret_cast<const float4*>(base + (size_t)l * E_);
        float a = al[l];
        acc.x += a * v.x; acc.y += a * v.y; acc.z += a * v.z; acc.w += a * v.w;
    }
    red[t] = acc;
    __syncthreads();
    if (t < 64) {
        float4 r0 = red[t], r1 = red[64 + t], r2 = red[128 + t], r3 = red[192 + t];
        float4 o;
        o.x = r0.x + r1.x + r2.x + r3.x;
        o.y = r0.y + r1.y + r2.y + r3.y;
        o.z = r0.z + r1.z + r2.z + r3.z;
        o.w = r0.w + r1.w + r2.w + r3.w;
        *reinterpret_cast<float4*>(awe + b * E_ + (ec << 8) + (t << 2)) = o;
    }
}

extern "C" void kernel_launch(void* const* d_in, const int* in_sizes, int n_in,
                              void* d_out, int out_size, void* d_ws, size_t ws_size,
                              hipStream_t stream) {
    const float* enc  = (const float*)d_in[0];
    const float* dec  = (const float*)d_in[1];
    const int*   mask = (const int*)d_in[2];
    const float* We   = (const float*)d_in[3];
    const float* be   = (const float*)d_in[4];
    const float* Wd   = (const float*)d_in[5];
    const float* bd   = (const float*)d_in[6];
    const float* wf   = (const float*)d_in[7];
    const float* bf   = (const float*)d_in[8];

    float* awe   = (float*)d_out;                  // [256][2048]
    float* alpha = awe + (size_t)B_ * E_;          // [256][196]

    char* ws = (char*)d_ws;
    unsigned short* WeP = (unsigned short*)ws;                        // 2 MB
    float* bias2   = (float*)(ws + 2097152);                          // 512 KB
    float* scoresP = (float*)(ws + 2621440);                          // 803 KB

    hipLaunchKernelGGL(k_wepack, dim3((E_ * A_) / 256), dim3(256), 0, stream, We, WeP);
    hipLaunchKernelGGL(k_bias2, dim3(B_ / 4), dim3(256), 0, stream, dec, Wd, be, bd, bias2);
    hipLaunchKernelGGL(k_gemm_score, dim3(1568), dim3(256), 0, stream,
                       enc, WeP, bias2, wf, scoresP);
    hipLaunchKernelGGL(k_softmax, dim3(B_), dim3(256), 0, stream, scoresP, mask, bf, alpha);
    hipLaunchKernelGGL(k_awe, dim3(8, B_), dim3(256), 0, stream, enc, alpha, awe);
}

// Round 13
// 537.217 us; speedup vs baseline: 1.0962x; 1.0395x over previous
//
#include <hip/hip_runtime.h>
#include <hip/hip_bf16.h>

// Attention_50946902065218: Bahdanau-style attention
// B=256, L=196, E=2048, D=1024, A=512
// v13 pipeline (= v12 with exact-coverage k_encbf):
//  k_wepack: We fp32 -> bf16, [kb][n][slot^swz(n)][e] pre-swizzled (2 MB)
//  k_encbf : enc fp32 -> bf16 ROW-MAJOR (201 MB ws) -- exact streaming copy
//  k_bias2 : bias2[b][a] = be + bd + dec@Wd (64 blocks x 4 batches)
//  k_gemm_score: m97-pure 128x128 tile, 4 waves 2x2, BK=32.
//     BOTH operands via global_load_lds (no staging registers, no in-loop cvt):
//       A: row-major bf16 encB, conflict-free XOR baked into per-lane SOURCE
//          chunk (LDS dest linear); B: pre-swizzled WeP slice (linear copy).
//     3-buf LDS, stage-ahead-2, counted vmcnt(4) raw barriers.
//     XCD-chunked swizzle (4 nt-siblings share A-panel in L2).
//  k_softmax: sum 4 partials + mask + softmax over L -> alpha
//  k_awe   : alpha-weighted sum reading row-major bf16 encB (205 MB)

#define B_ 256
#define L_ 196
#define E_ 2048
#define D_ 1024
#define A_ 512
#define M_TOT (B_ * L_)   // 50176 = 392 * 128

typedef __attribute__((ext_vector_type(8))) short bf16x8;
typedef __attribute__((ext_vector_type(4))) float f32x4;

static __device__ __forceinline__ unsigned short f2bf(float f) {
    union { float f; unsigned u; } u{f};
    unsigned r = u.u + 0x7fffu + ((u.u >> 16) & 1u);   // RNE
    return (unsigned short)(r >> 16);
}
static __device__ __forceinline__ unsigned int pk2(float x, float y) {
    __hip_bfloat162 h = __float22bfloat162_rn(float2{x, y});   // v_cvt_pk_bf16_f32
    return *reinterpret_cast<unsigned int*>(&h);
}
static __device__ __forceinline__ void gload_lds16(const void* g, void* l) {
    __builtin_amdgcn_global_load_lds(
        (const __attribute__((address_space(1))) unsigned int*)g,
        (__attribute__((address_space(3))) unsigned int*)l, 16, 0, 0);
}

// ---------------- k_wepack: We (E x A fp32) -> WeP bf16 ----------------------
// (k,n): kb=k>>5, slot=(k>>3)&3, e=k&7; stored slot' = slot ^ ((n>>1)&3).
// Index = kb*16384 + n*32 + slot'*8 + e.  (measured: 0 LDS conflicts, r4-r11)
__global__ __launch_bounds__(256) void k_wepack(const float* __restrict__ We,
                                                unsigned short* __restrict__ WeP) {
    int i = blockIdx.x * 256 + threadIdx.x;
    int k = i >> 9, n = i & 511;
    int kb = k >> 5, slot = (k >> 3) & 3, e = k & 7;
    int slotE = slot ^ ((n >> 1) & 3);
    WeP[(kb << 14) + (n << 5) + (slotE << 3) + e] = f2bf(We[i]);
}

// ---------------- k_encbf: enc fp32 -> bf16 row-major (streaming) ------------
// 6272 blocks x 256 thr x 8 iters x 8 elems = 102,760,448 = B*L*E  (EXACT)
__global__ __launch_bounds__(256) void k_encbf(const float* __restrict__ enc,
                                               unsigned short* __restrict__ encB) {
    size_t i = (size_t)(blockIdx.x * 256 + threadIdx.x) * 8;
    const size_t stride = (size_t)6272 * 256 * 8;
    #pragma unroll 4
    for (int it = 0; it < 8; it++) {
        float4 f0 = *reinterpret_cast<const float4*>(enc + i);
        float4 f1 = *reinterpret_cast<const float4*>(enc + i + 4);
        uint4 q;
        q.x = pk2(f0.x, f0.y); q.y = pk2(f0.z, f0.w);
        q.z = pk2(f1.x, f1.y); q.w = pk2(f1.z, f1.w);
        *reinterpret_cast<uint4*>(encB + i) = q;
        i += stride;
    }
}

// ---------------- k_bias2: bias2 = be + bd + dec @ Wd (4 batches/block) ------
__global__ __launch_bounds__(256) void k_bias2(const float* __restrict__ dec,
                                               const float* __restrict__ Wd,
                                               const float* __restrict__ be,
                                               const float* __restrict__ bd,
                                               float* __restrict__ bias2) {
    int b0 = blockIdx.x * 4, t = threadIdx.x;
    __shared__ float ds[4][D_];
    for (int i = t; i < 4 * D_; i += 256) ds[i >> 10][i & 1023] = dec[(size_t)b0 * D_ + i];
    __syncthreads();
    #pragma unroll
    for (int p = 0; p < 2; p++) {
        int a = p * 256 + t;
        float a0 = 0.f, a1 = 0.f, a2 = 0.f, a3 = 0.f;
        #pragma unroll 4
        for (int d = 0; d < D_; d++) {
            float w = Wd[d * A_ + a];
            a0 += ds[0][d] * w; a1 += ds[1][d] * w;
            a2 += ds[2][d] * w; a3 += ds[3][d] * w;
        }
        float bb = be[a] + bd[a];
        bias2[(b0 + 0) * A_ + a] = a0 + bb;
        bias2[(b0 + 1) * A_ + a] = a1 + bb;
        bias2[(b0 + 2) * A_ + a] = a2 + bb;
        bias2[(b0 + 3) * A_ + a] = a3 + bb;
    }
}

// ---------------- k_gemm_score v13 -------------------------------------------
// 1568 blocks (392 mt x 4 nt, XCD-chunked), 256 thr, 4 waves 2x2, wave 64x64.
// LDS: A bf16 3x8KB + B bf16 3x8KB + score 1KB = 49 KB -> 3 blocks/CU.
__global__ __launch_bounds__(256) void k_gemm_score(
        const unsigned short* __restrict__ encB,
        const unsigned short* __restrict__ WeP,
        const float* __restrict__ bias2,
        const float* __restrict__ wf,
        float* __restrict__ scoresP) {
    __shared__ __align__(16) unsigned short aL[3 * 4096];
    __shared__ __align__(16) unsigned short bL[3 * 4096];
    __shared__ float score_lds[4][64];

    const int tid = threadIdx.x;
    const int raw = blockIdx.x;                 // 1568 = 8 * 196
    const int wg = (raw & 7) * 196 + (raw >> 3);
    const int mt = wg >> 2, nt = wg & 3;
    const int m0 = mt * 128;

    const int lane = tid & 63, wid = tid >> 6;
    const int wm = wid >> 1, wn = wid & 1;
    const int kg = lane >> 4, lr = lane & 15;

    // A staging: A-tile 128 rows x 32 k x 2B = 8 KB = 256 thr x 2 x 16B.
    // dest 16B-slot gidx = c*256 + tid -> (row = gidx>>2, dest chunk = gidx&3).
    // Source chunk for that dest = (gidx&3) ^ ((row>>1)&3)  (XOR in SOURCE
    // address; LDS dest stays linear -- rule 21). Fragment read applies the
    // same XOR: chunk = kg ^ ((row>>1)&3)  (r11-measured: 0 conflicts).
    const int ar0 = tid >> 2;                   // row for c=0
    const int ac0 = (tid & 3) ^ ((ar0 >> 1) & 3);
    const int ar1 = (256 + tid) >> 2;           // row for c=1
    const int ac1 = (tid & 3) ^ ((ar1 >> 1) & 3);
    const unsigned short* aSrc0 = encB + (size_t)(m0 + ar0) * E_ + ac0 * 8;
    const unsigned short* aSrc1 = encB + (size_t)(m0 + ar1) * E_ + ac1 * 8;

    // B staging: linear copy of the block's pre-swizzled 8 KB nt-slice
    const unsigned short* bSrc = WeP + nt * 4096 + tid * 8;

    auto stage = [&](int kb, int buf) {
        const int off = buf << 12;
        gload_lds16(aSrc0 + (kb << 5), &aL[off + tid * 8]);
        gload_lds16(aSrc1 + (kb << 5), &aL[off + 2048 + tid * 8]);
        const unsigned short* sb = bSrc + (kb << 14);
        gload_lds16(sb,        &bL[off + tid * 8]);
        gload_lds16(sb + 2048, &bL[off + 2048 + tid * 8]);
    };

    f32x4 acc[4][4];
    #pragma unroll
    for (int i = 0; i < 4; i++)
        #pragma unroll
        for (int j = 0; j < 4; j++) acc[i][j] = (f32x4){0.f, 0.f, 0.f, 0.f};

    auto computeTile = [&](int buf) {
        const int off = buf << 12;
        bf16x8 bfr[4];
        #pragma unroll
        for (int j = 0; j < 4; j++) {
            int n = wn * 64 + j * 16 + lr;
            bfr[j] = *reinterpret_cast<const bf16x8*>(
                &bL[off + n * 32 + ((kg ^ ((n >> 1) & 3)) << 3)]);
        }
        #pragma unroll
        for (int i = 0; i < 4; i++) {
            int row = wm * 64 + i * 16 + lr;
            bf16x8 af = *reinterpret_cast<const bf16x8*>(
                &aL[off + row * 32 + ((kg ^ ((row >> 1) & 3)) << 3)]);
            #pragma unroll
            for (int j = 0; j < 4; j++)
                acc[i][j] = __builtin_amdgcn_mfma_f32_16x16x32_bf16(
                    af, bfr[j], acc[i][j], 0, 0, 0);
        }
    };

    // --- prologue: stage(0), stage(1); wait only stage(0) (vmcnt(4)) ---
    stage(0, 0);
    stage(1, 1);
    __builtin_amdgcn_sched_barrier(0);
    asm volatile("s_waitcnt vmcnt(4) lgkmcnt(0)" ::: "memory");
    __builtin_amdgcn_s_barrier();
    __builtin_amdgcn_sched_barrier(0);

    // --- main loop: stage(t+2) || compute(t); barrier waits stage(t+1) ---
    int cur = 0;
    for (int t = 0; t < 64; t++) {
        if (t < 62) {
            int nb = cur + 2; if (nb >= 3) nb -= 3;
            stage(t + 2, nb);
            __builtin_amdgcn_sched_barrier(0);
        }
        computeTile(cur);
        if (t < 63) {
            if (t < 62) {
                asm volatile("s_waitcnt vmcnt(4) lgkmcnt(0)" ::: "memory");
            } else {
                asm volatile("s_waitcnt vmcnt(0) lgkmcnt(0)" ::: "memory");
            }
            __builtin_amdgcn_s_barrier();
            __builtin_amdgcn_sched_barrier(0);
        }
        cur = (cur == 2) ? 0 : cur + 1;
    }

    // --- epilogue: tanh + wf dot over this block's 128 cols -> partials ---
    #pragma unroll
    for (int i = 0; i < 4; i++) {
        #pragma unroll
        for (int r = 0; r < 4; r++) {
            int Rw = i * 16 + kg * 4 + r;   // C/D: col=lane&15, row=(lane>>4)*4+reg
            int gm = m0 + wm * 64 + Rw;
            int bg = gm / L_;
            float sum = 0.f;
            #pragma unroll
            for (int j = 0; j < 4; j++) {
                int C = nt * 128 + wn * 64 + j * 16 + lr;
                float x = acc[i][j][r] + bias2[bg * A_ + C];
                float ex = __expf(2.f * x);     // tanh = 1 - 2/(e^2x + 1)
                sum += wf[C] * (1.f - 2.f * __builtin_amdgcn_rcpf(ex + 1.f));
            }
            #pragma unroll
            for (int mk = 1; mk < 16; mk <<= 1) sum += __shfl_xor(sum, mk);
            if (lr == 0) score_lds[wid][Rw] = sum;
        }
    }
    __syncthreads();
    if (tid < 128) {
        int wmp = tid >> 6, rl = tid & 63;
        float s = score_lds[wmp * 2][rl] + score_lds[wmp * 2 + 1][rl];
        scoresP[nt * M_TOT + m0 + wmp * 64 + rl] = s;
    }
}

// ---------------- k_softmax: sum 4 partials + mask + softmax -----------------
__global__ __launch_bounds__(256) void k_softmax(const float* __restrict__ scoresP,
                                                 const int* __restrict__ mask,
                                                 const float* __restrict__ bfp,
                                                 float* __restrict__ alpha) {
    int b = blockIdx.x, t = threadIdx.x;
    float bfv = bfp[0];
    float v = -INFINITY;
    if (t < L_) {
        int idx = b * L_ + t;
        float sc = scoresP[idx] + scoresP[M_TOT + idx] +
                   scoresP[2 * M_TOT + idx] + scoresP[3 * M_TOT + idx];
        v = (mask[idx] == 0) ? -1e9f : (sc + bfv);
    }
    __shared__ float redm[4], reds[4];
    float m = v;
    #pragma unroll
    for (int s = 1; s < 64; s <<= 1) m = fmaxf(m, __shfl_xor(m, s));
    int w = t >> 6;
    if ((t & 63) == 0) redm[w] = m;
    __syncthreads();
    m = fmaxf(fmaxf(redm[0], redm[1]), fmaxf(redm[2], redm[3]));
    float e = (t < L_) ? expf(v - m) : 0.f;
    float s = e;
    #pragma unroll
    for (int k = 1; k < 64; k <<= 1) s += __shfl_xor(s, k);
    if ((t & 63) == 0) reds[w] = s;
    __syncthreads();
    s = reds[0] + reds[1] + reds[2] + reds[3];
    if (t < L_) alpha[b * L_ + t] = e / s;
}

// ---------------- k_awe: awe = sum_l alpha * encB (bf16, row-major) ----------
// grid (4 e-chunks of 512, 256 batches), 256 thr = 4 L-groups x 64 lanes.
// Lane reads 16B (8 bf16) per row; wave reads 1 KB contiguous -- coalesced.
__global__ __launch_bounds__(256) void k_awe(const unsigned short* __restrict__ encB,
                                             const float* __restrict__ alpha,
                                             float* __restrict__ awe) {
    int b = blockIdx.y, ec = blockIdx.x, t = threadIdx.x;
    int g = t >> 6, lt = t & 63;
    __shared__ float al[L_];
    __shared__ float red[256][8];
    if (t < L_) al[t] = alpha[b * L_ + t];
    __syncthreads();
    int e0 = (ec << 9) + (lt << 3);
    const unsigned short* base = encB + (size_t)b * L_ * E_ + e0;
    float acc[8] = {0.f, 0.f, 0.f, 0.f, 0.f, 0.f, 0.f, 0.f};
    int l0 = g * 49;
    #pragma unroll 7
    for (int l = l0; l < l0 + 49; l++) {
        bf16x8 v = *reinterpret_cast<const bf16x8*>(base + (size_t)l * E_);
        float a = al[l];
        #pragma unroll
        for (int j = 0; j < 8; j++)
            acc[j] += a * __uint_as_float(((unsigned)(unsigned short)v[j]) << 16);
    }
    #pragma unroll
    for (int j = 0; j < 8; j++) red[t][j] = acc[j];
    __syncthreads();
    if (t < 64) {
        float o[8];
        #pragma unroll
        for (int j = 0; j < 8; j++)
            o[j] = (red[t][j] + red[64 + t][j]) + (red[128 + t][j] + red[192 + t][j]);
        float* dst = awe + (size_t)b * E_ + (ec << 9) + (t << 3);
        *reinterpret_cast<float4*>(dst)     = float4{o[0], o[1], o[2], o[3]};
        *reinterpret_cast<float4*>(dst + 4) = float4{o[4], o[5], o[6], o[7]};
    }
}

extern "C" void kernel_launch(void* const* d_in, const int* in_sizes, int n_in,
                              void* d_out, int out_size, void* d_ws, size_t ws_size,
                              hipStream_t stream) {
    const float* enc  = (const float*)d_in[0];
    const float* dec  = (const float*)d_in[1];
    const int*   mask = (const int*)d_in[2];
    const float* We   = (const float*)d_in[3];
    const float* be   = (const float*)d_in[4];
    const float* Wd   = (const float*)d_in[5];
    const float* bd   = (const float*)d_in[6];
    const float* wf   = (const float*)d_in[7];
    const float* bf   = (const float*)d_in[8];

    float* awe   = (float*)d_out;                  // [256][2048]
    float* alpha = awe + (size_t)B_ * E_;          // [256][196]

    char* ws = (char*)d_ws;
    unsigned short* WeP = (unsigned short*)ws;                 // @0,      2 MB
    float* bias2   = (float*)(ws + 2097152);                   // @2 MB,   512 KB
    float* scoresP = (float*)(ws + 2621440);                   // @2.5 MB, 803 KB
    unsigned short* encB = (unsigned short*)(ws + 4194304);    // @4 MB,   201 MB

    hipLaunchKernelGGL(k_wepack, dim3((E_ * A_) / 256), dim3(256), 0, stream, We, WeP);
    hipLaunchKernelGGL(k_encbf, dim3(6272), dim3(256), 0, stream, enc, encB);
    hipLaunchKernelGGL(k_bias2, dim3(B_ / 4), dim3(256), 0, stream, dec, Wd, be, bd, bias2);
    hipLaunchKernelGGL(k_gemm_score, dim3(1568), dim3(256), 0, stream,
                       encB, WeP, bias2, wf, scoresP);
    hipLaunchKernelGGL(k_softmax, dim3(B_), dim3(256), 0, stream, scoresP, mask, bf, alpha);
    hipLaunchKernelGGL(k_awe, dim3(4, B_), dim3(256), 0, stream, encB, alpha, awe);
}